// Round 7
// baseline (572.242 us; speedup 1.0000x reference)
//
#include <hip/hip_runtime.h>
#include <hip/hip_bf16.h>

// Problem: B=2,S=8192 -> TOK=16384 tokens; H=1024; DFF=4096.
// out[t] = mask[t] ? relu((h[t]*w[t]) @ W1 + b1) @ W2 + b2 : 0
// R11: gemm2 counted-vmcnt dbuf REVERTED (R10: 107->118.7, third pipelining
//     regression — LDS footprint costs more occupancy than prefetch buys).
//     Diagnosis: R6-gemm2 is LDS-throughput-bound (48 KiB ds-read/K-step =
//     576 cyc vs 310 cyc MFMA). Fix: B operand (W2t, L2-hot 8 MB) now loads
//     DIRECTLY global->registers (no LDS, no swizzle needed); LDS holds only
//     the 8 KiB A tile. LDS read/K-step 48->16 KiB -> MFMA becomes critical
//     path. Same 2-syncthreads structure (its vmcnt(0) drain guarantees the
//     b-loads landed). gemm1 + k_pre unchanged (R9-proven).

#define TOK 16384
#define HID 1024
#define FF  4096

typedef __attribute__((ext_vector_type(8))) __bf16 bf16x8;
typedef __attribute__((ext_vector_type(4))) float f32x4;

__device__ __forceinline__ void gload_lds16(const void* g, void* l) {
  // async global->LDS, 16B per lane; LDS dest = wave-uniform base + lane*16
  __builtin_amdgcn_global_load_lds((const __attribute__((address_space(1))) void*)g,
                                   (__attribute__((address_space(3))) void*)l, 16, 0, 0);
}

// ---------------- fused pre-pass: W1^T, W2^T, gate+compact ----------------
// Block ranges: [0,1024) transpose W1 (64x64 tiles), [1024,2048) transpose W2,
// [2048,3072) gate (16 tokens/block). One dispatch -> phases overlap on-chip.
#define GTOK 16
#define NBT1 1024  // (FF/64)*(HID/64)
#define NBT2 1024  // (HID/64)*(FF/64)

__global__ __launch_bounds__(256) void k_pre(const float* __restrict__ W1,
                                             __hip_bfloat16* __restrict__ W1t,
                                             const float* __restrict__ W2,
                                             __hip_bfloat16* __restrict__ W2t,
                                             const float* __restrict__ h,
                                             const float* __restrict__ wg,
                                             const float* __restrict__ bgp,
                                             const int* __restrict__ labels,
                                             float* __restrict__ out,
                                             __hip_bfloat16* __restrict__ A,
                                             int* __restrict__ idx,
                                             int* __restrict__ cnt) {
  const int bid = blockIdx.x;
  const int tid = threadIdx.x;

  if (bid < NBT1 + NBT2) {
    // -------- transpose: src[R][C] fp32 -> dst[C][R] bf16 --------
    const float* src;
    __hip_bfloat16* dst;
    int R, C, tb;
    if (bid < NBT1) { src = W1; dst = W1t; R = HID; C = FF;  tb = bid; }
    else            { src = W2; dst = W2t; R = FF;  C = HID; tb = bid - NBT1; }
    const int nbc = C / 64;
    const int c0 = (tb % nbc) * 64, r0 = (tb / nbc) * 64;
    __shared__ float tile[64][65];        // stride 65: conflict-free col reads
    const int tx = tid & 63, ty = tid >> 6;
#pragma unroll
    for (int i = 0; i < 16; ++i)
      tile[ty + i * 4][tx] = src[(size_t)(r0 + ty + i * 4) * C + (c0 + tx)];
    __syncthreads();
#pragma unroll
    for (int i = 0; i < 16; ++i)
      dst[(size_t)(c0 + ty + i * 4) * R + (r0 + tx)] =
          __float2bfloat16(tile[tx][ty + i * 4]);
    return;
  }

  // -------- gate + compact + zero dropped rows --------
  const int gb = bid - (NBT1 + NBT2);
  const int t0 = gb * GTOK;
  const int wave = tid >> 6, lane = tid & 63;

  float4 gv[4];
#pragma unroll
  for (int it = 0; it < 4; ++it) gv[it] = ((const float4*)wg)[it * 64 + lane];

  // hold h rows in registers across both passes (64 VGPR)
  float4 hv[4][4];
  __shared__ float slogit[GTOK];
  __shared__ int sslot[GTOK];

#pragma unroll
  for (int r = 0; r < 4; ++r) {
    const int li = r * 4 + wave;
    const float* hrow = h + (size_t)(t0 + li) * HID;
    float d = 0.f;
#pragma unroll
    for (int it = 0; it < 4; ++it) {
      hv[r][it] = ((const float4*)hrow)[it * 64 + lane];
      d += hv[r][it].x * gv[it].x + hv[r][it].y * gv[it].y +
           hv[r][it].z * gv[it].z + hv[r][it].w * gv[it].w;
    }
#pragma unroll
    for (int o = 32; o > 0; o >>= 1) d += __shfl_down(d, o, 64);
    if (lane == 0) slogit[li] = d;
  }
  __syncthreads();

  if (tid == 0) {  // prefix over 16 keep flags; ONE atomic per block
    const float bg = bgp[0];
    int slots[GTOK];
    int n = 0;
#pragma unroll
    for (int li = 0; li < GTOK; ++li) {
      const bool keep = (slogit[li] + bg >= 0.0f) || (labels[t0 + li] == -100);
      slots[li] = keep ? n++ : -1;
    }
    const int base = atomicAdd(cnt, n);
#pragma unroll
    for (int li = 0; li < GTOK; ++li)
      sslot[li] = slots[li] >= 0 ? base + slots[li] : -1;
  }
  __syncthreads();

#pragma unroll
  for (int r = 0; r < 4; ++r) {
    const int li = r * 4 + wave;
    const int t = t0 + li;
    const int m = sslot[li];
    if (m >= 0) {
      if (lane == 0) idx[m] = t;
      const float logit = slogit[li] + bgp[0];
      const float w = 1.0f / (1.0f + __expf(-logit));
#pragma unroll
      for (int it = 0; it < 4; ++it) {
        union { ushort4 u; __hip_bfloat16 b[4]; } pk;
        pk.b[0] = __float2bfloat16(hv[r][it].x * w);
        pk.b[1] = __float2bfloat16(hv[r][it].y * w);
        pk.b[2] = __float2bfloat16(hv[r][it].z * w);
        pk.b[3] = __float2bfloat16(hv[r][it].w * w);
        ((ushort4*)(A + (size_t)m * HID))[it * 64 + lane] = pk.u;
      }
    } else {
      const float4 z = make_float4(0.f, 0.f, 0.f, 0.f);
#pragma unroll
      for (int it = 0; it < 4; ++it)
        ((float4*)(out + (size_t)t * HID))[it * 64 + lane] = z;
    }
  }
}

// ---------------- GEMM A-tile swizzle ----------------
// LDS rows of 64 k-elems (128 B). Staging: lane l covers row
// r = wbase + c*8 + (l>>3), source chunk g = (l&7) ^ (r&7), stored at
// position l&7. Read of chunk ck of row r at position ck ^ (r&7); fragment
// rows have r&7 == fm&7 -> per-quad lanes cover all 8 bank-quads (2-way
// aliasing = free; measured 0 conflicts).

// GEMM1: Act = relu(A @ W1t^T + b1), bf16 out. K=HID=1024. 128x128 tile,
// single-buffered: 2304 active blocks (~9/CU) -> cross-block overlap covers
// the global->LDS latency (R6-proven structure). UNCHANGED.
__global__ __launch_bounds__(256, 2) void k_gemm1(const __hip_bfloat16* __restrict__ A,
                                                  const __hip_bfloat16* __restrict__ Bt,
                                                  const float* __restrict__ bias,
                                                  __hip_bfloat16* __restrict__ Act,
                                                  const int* __restrict__ cnt) {
  const int Mc = *cnt;
  const int m0 = blockIdx.x * 128;
  if (m0 >= Mc) return;
  const int n0 = blockIdx.y * 128;

  __shared__ __hip_bfloat16 lA[128 * 64];  // 16 KiB
  __shared__ __hip_bfloat16 lB[128 * 64];  // 16 KiB

  const int tid = threadIdx.x;
  const int wave = tid >> 6, lane = tid & 63;
  const int wr = (wave >> 1) * 64, wc = (wave & 1) * 64;
  const int fm = lane & 15, quad = lane >> 4;

  const int srow = (lane >> 3);                       // 0..7
  const int sg   = ((lane & 7) ^ srow) * 8;           // global elem offset

  f32x4 acc[4][4] = {};

  const __hip_bfloat16* gA = A  + (size_t)(m0 + wave * 32 + srow) * HID + sg;
  const __hip_bfloat16* gB = Bt + (size_t)(n0 + wave * 32 + srow) * HID + sg;
  char* dA = (char*)lA + wave * 4096;
  char* dB = (char*)lB + wave * 4096;

  for (int kt = 0; kt < HID; kt += 64) {
    __syncthreads();
#pragma unroll
    for (int c = 0; c < 4; ++c) {
      gload_lds16(gA + (size_t)(c * 8) * HID + kt, dA + c * 1024);
      gload_lds16(gB + (size_t)(c * 8) * HID + kt, dB + c * 1024);
    }
    __syncthreads();
#pragma unroll
    for (int ks = 0; ks < 2; ++ks) {
      bf16x8 af[4], bb[4];
#pragma unroll
      for (int i = 0; i < 4; ++i)
        af[i] = *(const bf16x8*)&lA[(wr + i * 16 + fm) * 64 + (((ks * 4 + quad) ^ (fm & 7)) * 8)];
#pragma unroll
      for (int j = 0; j < 4; ++j)
        bb[j] = *(const bf16x8*)&lB[(wc + j * 16 + fm) * 64 + (((ks * 4 + quad) ^ (fm & 7)) * 8)];
#pragma unroll
      for (int i = 0; i < 4; ++i)
#pragma unroll
        for (int j = 0; j < 4; ++j)
          acc[i][j] = __builtin_amdgcn_mfma_f32_16x16x32_bf16(af[i], bb[j], acc[i][j], 0, 0, 0);
    }
  }

#pragma unroll
  for (int j = 0; j < 4; ++j) {
    const int col = n0 + wc + j * 16 + fm;
    const float bv = bias[col];
#pragma unroll
    for (int i = 0; i < 4; ++i) {
      const int rbase = m0 + wr + i * 16 + quad * 4;
#pragma unroll
      for (int r = 0; r < 4; ++r) {
        float v = acc[i][j][r] + bv;
        v = v > 0.f ? v : 0.f;
        Act[(size_t)(rbase + r) * FF + col] = __float2bfloat16(v);
      }
    }
  }
}

// GEMM2: out[idx[m]] = Act @ W2t^T + b2, fp32 scatter. K=FF=4096.
// BM=64 x BN=128, single-buffered, B DIRECT-TO-REGISTER:
// A (Act rows) staged in 8 KiB LDS with XOR swizzle; B fragments loaded
// straight from W2t (L2/L3-hot, 8 MB) into bb0/bb1 regs each K-step —
// identical values to the old staged path, no swizzle needed. Issued before
// the staging __syncthreads, whose vmcnt(0) drain guarantees completion.
// LDS read/K-step: 16 KiB (188 cyc) < MFMA (310 cyc) -> MFMA-bound.
__global__ __launch_bounds__(256, 4) void k_gemm2(const __hip_bfloat16* __restrict__ Act,
                                                  const __hip_bfloat16* __restrict__ Bt,
                                                  const float* __restrict__ bias,
                                                  const int* __restrict__ idx,
                                                  float* __restrict__ out,
                                                  const int* __restrict__ cnt) {
  const int Mc = *cnt;
  const int m0 = blockIdx.x * 64;
  if (m0 >= Mc) return;
  const int n0 = blockIdx.y * 128;

  __shared__ __hip_bfloat16 lA[64 * 64];   // 8 KiB (A only)

  const int tid = threadIdx.x;
  const int wave = tid >> 6, lane = tid & 63;
  const int wr = (wave >> 1) * 32, wc = (wave & 1) * 64;
  const int fm = lane & 15, quad = lane >> 4;
  const int srow = (lane >> 3);
  const int sg   = ((lane & 7) ^ srow) * 8;

  f32x4 acc[2][4] = {};

  const __hip_bfloat16* gA = Act + (size_t)(m0 + wave * 16 + srow) * FF + sg;
  // per-lane B source: row n0+wc+j*16+fm, k-offset kt + (ks*4+quad)*8
  const __hip_bfloat16* gBlane = Bt + (size_t)(n0 + wc + fm) * FF + quad * 8;
  char* dA = (char*)lA + wave * 2048;

  for (int kt = 0; kt < FF; kt += 64) {
    __syncthreads();
    // stage A tile (2 async calls)
    gload_lds16(gA + kt, dA);
    gload_lds16(gA + (size_t)8 * FF + kt, dA + 1024);
    // direct B loads: bb0 = ks0 chunk (quad*8), bb1 = ks1 chunk (+32 elems)
    bf16x8 bb0[4], bb1[4];
#pragma unroll
    for (int j = 0; j < 4; ++j) {
      const __hip_bfloat16* bp = gBlane + (size_t)(j * 16) * FF + kt;
      bb0[j] = *(const bf16x8*)bp;
      bb1[j] = *(const bf16x8*)(bp + 32);
    }
    __syncthreads();  // vmcnt(0) drain: A in LDS, bb0/bb1 in regs
#pragma unroll
    for (int ks = 0; ks < 2; ++ks) {
      bf16x8 af[2];
#pragma unroll
      for (int i = 0; i < 2; ++i)
        af[i] = *(const bf16x8*)&lA[(wr + i * 16 + fm) * 64 + (((ks * 4 + quad) ^ (fm & 7)) * 8)];
#pragma unroll
      for (int i = 0; i < 2; ++i)
#pragma unroll
        for (int j = 0; j < 4; ++j)
          acc[i][j] = __builtin_amdgcn_mfma_f32_16x16x32_bf16(
              af[i], ks == 0 ? bb0[j] : bb1[j], acc[i][j], 0, 0, 0);
    }
  }

#pragma unroll
  for (int i = 0; i < 2; ++i) {
#pragma unroll
    for (int r = 0; r < 4; ++r) {
      const int m = m0 + wr + i * 16 + quad * 4 + r;
      if (m < Mc) {
        const int t = idx[m];
        float* orow = out + (size_t)t * HID + n0 + wc + fm;
#pragma unroll
        for (int j = 0; j < 4; ++j)
          orow[j * 16] = acc[i][j][r] + bias[n0 + wc + j * 16 + fm];
      }
    }
  }
}

// ---------------- launch ----------------
extern "C" void kernel_launch(void* const* d_in, const int* in_sizes, int n_in,
                              void* d_out, int out_size, void* d_ws, size_t ws_size,
                              hipStream_t stream) {
  const float* h   = (const float*)d_in[0];
  const float* Wg  = (const float*)d_in[3];
  const float* bg  = (const float*)d_in[4];
  const float* W1  = (const float*)d_in[5];
  const float* b1  = (const float*)d_in[6];
  const float* W2  = (const float*)d_in[7];
  const float* b2  = (const float*)d_in[8];
  const int*  labels = (const int*)d_in[9];
  float* out = (float*)d_out;

  char* ws = (char*)d_ws;
  int* cnt            = (int*)(ws + 0);
  int* idx            = (int*)(ws + 1024);
  __hip_bfloat16* W1t = (__hip_bfloat16*)(ws + (1u  << 17));   // [FF][HID]
  __hip_bfloat16* W2t = (__hip_bfloat16*)(ws + (16u << 20));   // [HID][FF]
  __hip_bfloat16* A   = (__hip_bfloat16*)(ws + (32u << 20));   // [TOK][HID]
  __hip_bfloat16* Act = (__hip_bfloat16*)(ws + (64ull << 20)); // [TOK][FF]

  hipMemsetAsync(cnt, 0, 4, stream);
  k_pre<<<NBT1 + NBT2 + TOK / GTOK, 256, 0, stream>>>(W1, W1t, W2, W2t, h, Wg,
                                                      bg, labels, out, A, idx, cnt);
  k_gemm1<<<dim3(TOK / 128, FF / 128), 256, 0, stream>>>(A, W1t, b1, Act, cnt);
  k_gemm2<<<dim3(TOK / 64, HID / 128), 256, 0, stream>>>(Act, W2t, b2, idx, out, cnt);
}

// Round 8
// 379.339 us; speedup vs baseline: 1.5085x; 1.5085x over previous
//
#include <hip/hip_runtime.h>
#include <hip/hip_bf16.h>

// Problem: B=2,S=8192 -> TOK=16384 tokens; H=1024; DFF=4096.
// out[t] = mask[t] ? relu((h[t]*w[t]) @ W1 + b1) @ W2 + b2 : 0
// R12: direct-to-reg B REVERTED (R11: 107->330us — VGPR=56 shows compiler
//     sank B-loads into the MFMA loop -> 8 serialized L2 latencies/K-step).
//     gemm2 restructured instead: 2 waves x (64x64 out) using
//     mfma_f32_32x32x16_bf16 (2x2 tiles, acc 4xf32x16). Same 64x128 block,
//     same 24 KiB LDS, same 2-barrier loop — but LDS read/K-step drops
//     48->32 KiB (376 cyc) and MFMA runs at the 32x32 rate (258 cyc):
//     the LDS-bound gap shrinks 1.86x -> 1.46x. 128-thread blocks.
//     gemm1 + k_pre unchanged (R9-proven).

#define TOK 16384
#define HID 1024
#define FF  4096

typedef __attribute__((ext_vector_type(8))) __bf16 bf16x8;
typedef __attribute__((ext_vector_type(4))) float f32x4;
typedef __attribute__((ext_vector_type(16))) float f32x16;

__device__ __forceinline__ void gload_lds16(const void* g, void* l) {
  // async global->LDS, 16B per lane; LDS dest = wave-uniform base + lane*16
  __builtin_amdgcn_global_load_lds((const __attribute__((address_space(1))) void*)g,
                                   (__attribute__((address_space(3))) void*)l, 16, 0, 0);
}

// ---------------- fused pre-pass: W1^T, W2^T, gate+compact ----------------
// Block ranges: [0,1024) transpose W1 (64x64 tiles), [1024,2048) transpose W2,
// [2048,3072) gate (16 tokens/block). One dispatch -> phases overlap on-chip.
#define GTOK 16
#define NBT1 1024  // (FF/64)*(HID/64)
#define NBT2 1024  // (HID/64)*(FF/64)

__global__ __launch_bounds__(256) void k_pre(const float* __restrict__ W1,
                                             __hip_bfloat16* __restrict__ W1t,
                                             const float* __restrict__ W2,
                                             __hip_bfloat16* __restrict__ W2t,
                                             const float* __restrict__ h,
                                             const float* __restrict__ wg,
                                             const float* __restrict__ bgp,
                                             const int* __restrict__ labels,
                                             float* __restrict__ out,
                                             __hip_bfloat16* __restrict__ A,
                                             int* __restrict__ idx,
                                             int* __restrict__ cnt) {
  const int bid = blockIdx.x;
  const int tid = threadIdx.x;

  if (bid < NBT1 + NBT2) {
    // -------- transpose: src[R][C] fp32 -> dst[C][R] bf16 --------
    const float* src;
    __hip_bfloat16* dst;
    int R, C, tb;
    if (bid < NBT1) { src = W1; dst = W1t; R = HID; C = FF;  tb = bid; }
    else            { src = W2; dst = W2t; R = FF;  C = HID; tb = bid - NBT1; }
    const int nbc = C / 64;
    const int c0 = (tb % nbc) * 64, r0 = (tb / nbc) * 64;
    __shared__ float tile[64][65];        // stride 65: conflict-free col reads
    const int tx = tid & 63, ty = tid >> 6;
#pragma unroll
    for (int i = 0; i < 16; ++i)
      tile[ty + i * 4][tx] = src[(size_t)(r0 + ty + i * 4) * C + (c0 + tx)];
    __syncthreads();
#pragma unroll
    for (int i = 0; i < 16; ++i)
      dst[(size_t)(c0 + ty + i * 4) * R + (r0 + tx)] =
          __float2bfloat16(tile[tx][ty + i * 4]);
    return;
  }

  // -------- gate + compact + zero dropped rows --------
  const int gb = bid - (NBT1 + NBT2);
  const int t0 = gb * GTOK;
  const int wave = tid >> 6, lane = tid & 63;

  float4 gv[4];
#pragma unroll
  for (int it = 0; it < 4; ++it) gv[it] = ((const float4*)wg)[it * 64 + lane];

  // hold h rows in registers across both passes (64 VGPR)
  float4 hv[4][4];
  __shared__ float slogit[GTOK];
  __shared__ int sslot[GTOK];

#pragma unroll
  for (int r = 0; r < 4; ++r) {
    const int li = r * 4 + wave;
    const float* hrow = h + (size_t)(t0 + li) * HID;
    float d = 0.f;
#pragma unroll
    for (int it = 0; it < 4; ++it) {
      hv[r][it] = ((const float4*)hrow)[it * 64 + lane];
      d += hv[r][it].x * gv[it].x + hv[r][it].y * gv[it].y +
           hv[r][it].z * gv[it].z + hv[r][it].w * gv[it].w;
    }
#pragma unroll
    for (int o = 32; o > 0; o >>= 1) d += __shfl_down(d, o, 64);
    if (lane == 0) slogit[li] = d;
  }
  __syncthreads();

  if (tid == 0) {  // prefix over 16 keep flags; ONE atomic per block
    const float bg = bgp[0];
    int slots[GTOK];
    int n = 0;
#pragma unroll
    for (int li = 0; li < GTOK; ++li) {
      const bool keep = (slogit[li] + bg >= 0.0f) || (labels[t0 + li] == -100);
      slots[li] = keep ? n++ : -1;
    }
    const int base = atomicAdd(cnt, n);
#pragma unroll
    for (int li = 0; li < GTOK; ++li)
      sslot[li] = slots[li] >= 0 ? base + slots[li] : -1;
  }
  __syncthreads();

#pragma unroll
  for (int r = 0; r < 4; ++r) {
    const int li = r * 4 + wave;
    const int t = t0 + li;
    const int m = sslot[li];
    if (m >= 0) {
      if (lane == 0) idx[m] = t;
      const float logit = slogit[li] + bgp[0];
      const float w = 1.0f / (1.0f + __expf(-logit));
#pragma unroll
      for (int it = 0; it < 4; ++it) {
        union { ushort4 u; __hip_bfloat16 b[4]; } pk;
        pk.b[0] = __float2bfloat16(hv[r][it].x * w);
        pk.b[1] = __float2bfloat16(hv[r][it].y * w);
        pk.b[2] = __float2bfloat16(hv[r][it].z * w);
        pk.b[3] = __float2bfloat16(hv[r][it].w * w);
        ((ushort4*)(A + (size_t)m * HID))[it * 64 + lane] = pk.u;
      }
    } else {
      const float4 z = make_float4(0.f, 0.f, 0.f, 0.f);
#pragma unroll
      for (int it = 0; it < 4; ++it)
        ((float4*)(out + (size_t)t * HID))[it * 64 + lane] = z;
    }
  }
}

// ---------------- GEMM LDS swizzle (both GEMMs) ----------------
// LDS rows of 64 k-elems (128 B). Staging: lane l covers row
// r = wbase + c*8 + (l>>3), source chunk g = (l&7) ^ (r&7), stored at
// position l&7. Read of chunk ck of row r at position ck ^ (r&7); fragment
// rows always have r&7 == lane&7 -> lanes spread across all 8 bank-quads
// (measured 0 conflicts).

// GEMM1: Act = relu(A @ W1t^T + b1), bf16 out. K=HID=1024. 128x128 tile,
// single-buffered: 2304 active blocks (~9/CU) -> cross-block overlap covers
// the global->LDS latency (R6-proven structure). UNCHANGED.
__global__ __launch_bounds__(256, 2) void k_gemm1(const __hip_bfloat16* __restrict__ A,
                                                  const __hip_bfloat16* __restrict__ Bt,
                                                  const float* __restrict__ bias,
                                                  __hip_bfloat16* __restrict__ Act,
                                                  const int* __restrict__ cnt) {
  const int Mc = *cnt;
  const int m0 = blockIdx.x * 128;
  if (m0 >= Mc) return;
  const int n0 = blockIdx.y * 128;

  __shared__ __hip_bfloat16 lA[128 * 64];  // 16 KiB
  __shared__ __hip_bfloat16 lB[128 * 64];  // 16 KiB

  const int tid = threadIdx.x;
  const int wave = tid >> 6, lane = tid & 63;
  const int wr = (wave >> 1) * 64, wc = (wave & 1) * 64;
  const int fm = lane & 15, quad = lane >> 4;

  const int srow = (lane >> 3);                       // 0..7
  const int sg   = ((lane & 7) ^ srow) * 8;           // global elem offset

  f32x4 acc[4][4] = {};

  const __hip_bfloat16* gA = A  + (size_t)(m0 + wave * 32 + srow) * HID + sg;
  const __hip_bfloat16* gB = Bt + (size_t)(n0 + wave * 32 + srow) * HID + sg;
  char* dA = (char*)lA + wave * 4096;
  char* dB = (char*)lB + wave * 4096;

  for (int kt = 0; kt < HID; kt += 64) {
    __syncthreads();
#pragma unroll
    for (int c = 0; c < 4; ++c) {
      gload_lds16(gA + (size_t)(c * 8) * HID + kt, dA + c * 1024);
      gload_lds16(gB + (size_t)(c * 8) * HID + kt, dB + c * 1024);
    }
    __syncthreads();
#pragma unroll
    for (int ks = 0; ks < 2; ++ks) {
      bf16x8 af[4], bb[4];
#pragma unroll
      for (int i = 0; i < 4; ++i)
        af[i] = *(const bf16x8*)&lA[(wr + i * 16 + fm) * 64 + (((ks * 4 + quad) ^ (fm & 7)) * 8)];
#pragma unroll
      for (int j = 0; j < 4; ++j)
        bb[j] = *(const bf16x8*)&lB[(wc + j * 16 + fm) * 64 + (((ks * 4 + quad) ^ (fm & 7)) * 8)];
#pragma unroll
      for (int i = 0; i < 4; ++i)
#pragma unroll
        for (int j = 0; j < 4; ++j)
          acc[i][j] = __builtin_amdgcn_mfma_f32_16x16x32_bf16(af[i], bb[j], acc[i][j], 0, 0, 0);
    }
  }

#pragma unroll
  for (int j = 0; j < 4; ++j) {
    const int col = n0 + wc + j * 16 + fm;
    const float bv = bias[col];
#pragma unroll
    for (int i = 0; i < 4; ++i) {
      const int rbase = m0 + wr + i * 16 + quad * 4;
#pragma unroll
      for (int r = 0; r < 4; ++r) {
        float v = acc[i][j][r] + bv;
        v = v > 0.f ? v : 0.f;
        Act[(size_t)(rbase + r) * FF + col] = __float2bfloat16(v);
      }
    }
  }
}

// GEMM2: out[idx[m]] = Act @ W2t^T + b2, fp32 scatter. K=FF=4096.
// BM=64 x BN=128, 2 waves x (64x64 out), mfma_f32_32x32x16_bf16 (2x2 of
// 32x32 tiles, acc 4xf32x16). Per-wave LDS read/K-step 256B/lane for
// 524288 FLOP (vs 192B for 262144 at R6 geometry) -> block LDS 48->32 KiB.
// Fragment layouts: A/B lane -> (row=lane&31, k-half=(lane>>5)*8);
// C/D row=(reg&3)+8*(reg>>2)+4*(lane>>5), col=lane&31.
// Same 2-syncthreads single-buffer loop (R6-proven sync structure).
__global__ __launch_bounds__(128, 3) void k_gemm2(const __hip_bfloat16* __restrict__ Act,
                                                  const __hip_bfloat16* __restrict__ Bt,
                                                  const float* __restrict__ bias,
                                                  const int* __restrict__ idx,
                                                  float* __restrict__ out,
                                                  const int* __restrict__ cnt) {
  const int Mc = *cnt;
  const int m0 = blockIdx.x * 64;
  if (m0 >= Mc) return;
  const int n0 = blockIdx.y * 128;

  __shared__ __hip_bfloat16 lA[64 * 64];   // 8 KiB
  __shared__ __hip_bfloat16 lB[128 * 64];  // 16 KiB

  const int tid = threadIdx.x;
  const int wave = tid >> 6, lane = tid & 63;
  const int col31 = lane & 31, half = lane >> 5;   // C/D col, k-half
  const int srow = (lane >> 3);
  const int sg   = ((lane & 7) ^ srow) * 8;

  f32x16 acc[2][2] = {};

  // staging: wave stages A rows [wave*32, +32) (4 calls) and
  // B rows [wave*64, +64) (8 calls)
  const __hip_bfloat16* gA = Act + (size_t)(m0 + wave * 32 + srow) * FF + sg;
  const __hip_bfloat16* gB = Bt  + (size_t)(n0 + wave * 64 + srow) * FF + sg;
  char* dA = (char*)lA + wave * 4096;
  char* dB = (char*)lB + wave * 8192;

  for (int kt = 0; kt < FF; kt += 64) {
    __syncthreads();
#pragma unroll
    for (int c = 0; c < 4; ++c)
      gload_lds16(gA + (size_t)(c * 8) * FF + kt, dA + c * 1024);
#pragma unroll
    for (int c = 0; c < 8; ++c)
      gload_lds16(gB + (size_t)(c * 8) * FF + kt, dB + c * 1024);
    __syncthreads();
#pragma unroll
    for (int ks = 0; ks < 4; ++ks) {        // 4 x K=16 sub-steps
      const int pos = ((ks * 2 + half) ^ (lane & 7)) * 8;
      bf16x8 af[2], bb[2];
#pragma unroll
      for (int ti = 0; ti < 2; ++ti)
        af[ti] = *(const bf16x8*)&lA[(ti * 32 + col31) * 64 + pos];
#pragma unroll
      for (int tj = 0; tj < 2; ++tj)
        bb[tj] = *(const bf16x8*)&lB[(wave * 64 + tj * 32 + col31) * 64 + pos];
#pragma unroll
      for (int ti = 0; ti < 2; ++ti)
#pragma unroll
        for (int tj = 0; tj < 2; ++tj)
          acc[ti][tj] = __builtin_amdgcn_mfma_f32_32x32x16_bf16(
              af[ti], bb[tj], acc[ti][tj], 0, 0, 0);
    }
  }

  float bv[2];
#pragma unroll
  for (int tj = 0; tj < 2; ++tj)
    bv[tj] = bias[n0 + wave * 64 + tj * 32 + col31];

#pragma unroll
  for (int ti = 0; ti < 2; ++ti) {
#pragma unroll
    for (int reg = 0; reg < 16; ++reg) {
      const int m = m0 + ti * 32 + (reg & 3) + 8 * (reg >> 2) + 4 * half;
      if (m < Mc) {
        const int t = idx[m];
        float* orow = out + (size_t)t * HID + n0 + wave * 64 + col31;
#pragma unroll
        for (int tj = 0; tj < 2; ++tj)
          orow[tj * 32] = acc[ti][tj][reg] + bv[tj];
      }
    }
  }
}

// ---------------- launch ----------------
extern "C" void kernel_launch(void* const* d_in, const int* in_sizes, int n_in,
                              void* d_out, int out_size, void* d_ws, size_t ws_size,
                              hipStream_t stream) {
  const float* h   = (const float*)d_in[0];
  const float* Wg  = (const float*)d_in[3];
  const float* bg  = (const float*)d_in[4];
  const float* W1  = (const float*)d_in[5];
  const float* b1  = (const float*)d_in[6];
  const float* W2  = (const float*)d_in[7];
  const float* b2  = (const float*)d_in[8];
  const int*  labels = (const int*)d_in[9];
  float* out = (float*)d_out;

  char* ws = (char*)d_ws;
  int* cnt            = (int*)(ws + 0);
  int* idx            = (int*)(ws + 1024);
  __hip_bfloat16* W1t = (__hip_bfloat16*)(ws + (1u  << 17));   // [FF][HID]
  __hip_bfloat16* W2t = (__hip_bfloat16*)(ws + (16u << 20));   // [HID][FF]
  __hip_bfloat16* A   = (__hip_bfloat16*)(ws + (32u << 20));   // [TOK][HID]
  __hip_bfloat16* Act = (__hip_bfloat16*)(ws + (64ull << 20)); // [TOK][FF]

  hipMemsetAsync(cnt, 0, 4, stream);
  k_pre<<<NBT1 + NBT2 + TOK / GTOK, 256, 0, stream>>>(W1, W1t, W2, W2t, h, Wg,
                                                      bg, labels, out, A, idx, cnt);
  k_gemm1<<<dim3(TOK / 128, FF / 128), 256, 0, stream>>>(A, W1t, b1, Act, cnt);
  k_gemm2<<<dim3(TOK / 64, HID / 128), 128, 0, stream>>>(Act, W2t, b2, idx, out, cnt);
}

// Round 9
// 365.479 us; speedup vs baseline: 1.5657x; 1.0379x over previous
//
#include <hip/hip_runtime.h>
#include <hip/hip_bf16.h>

// Problem: B=2,S=8192 -> TOK=16384 tokens; H=1024; DFF=4096.
// out[t] = mask[t] ? relu((h[t]*w[t]) @ W1 + b1) @ W2 + b2 : 0
// R13: 32x32-MFMA gemm2 REVERTED (R12: 9.3M bank conflicts — 32-rows-per-
//     chunk reads are 4-way-conflicted under any row&7 XOR store swizzle;
//     16x16's 16-rows x 4-chunks pattern is the conflict-free class).
//     gemm2 = exact R6 (106.8us plateau; 6 variants measured, all worse).
//     NEW: W2-transpose folded into gemm1's dispatch (blocks 0..1023) —
//     W2t is only needed by gemm2, so these memory-bound blocks overlap
//     gemm1's compute for free; k_pre = W1t + gate only.

#define TOK 16384
#define HID 1024
#define FF  4096

typedef __attribute__((ext_vector_type(8))) __bf16 bf16x8;
typedef __attribute__((ext_vector_type(4))) float f32x4;

__device__ __forceinline__ void gload_lds16(const void* g, void* l) {
  // async global->LDS, 16B per lane; LDS dest = wave-uniform base + lane*16
  __builtin_amdgcn_global_load_lds((const __attribute__((address_space(1))) void*)g,
                                   (__attribute__((address_space(3))) void*)l, 16, 0, 0);
}

// ---------------- k_pre: W1^T + gate+compact (one dispatch) ----------------
// Blocks [0,1024): transpose W1 (64x64 tiles); [1024,2048): gate 16 tok/blk.
#define GTOK 16
#define NBT1 1024  // (FF/64)*(HID/64)

__global__ __launch_bounds__(256) void k_pre(const float* __restrict__ W1,
                                             __hip_bfloat16* __restrict__ W1t,
                                             const float* __restrict__ h,
                                             const float* __restrict__ wg,
                                             const float* __restrict__ bgp,
                                             const int* __restrict__ labels,
                                             float* __restrict__ out,
                                             __hip_bfloat16* __restrict__ A,
                                             int* __restrict__ idx,
                                             int* __restrict__ cnt) {
  const int bid = blockIdx.x;
  const int tid = threadIdx.x;

  if (bid < NBT1) {
    // -------- transpose W1[HID][FF] fp32 -> W1t[FF][HID] bf16 --------
    const int nbc = FF / 64;
    const int c0 = (bid % nbc) * 64, r0 = (bid / nbc) * 64;
    __shared__ float tile[64][65];        // stride 65: conflict-free col reads
    const int tx = tid & 63, ty = tid >> 6;
#pragma unroll
    for (int i = 0; i < 16; ++i)
      tile[ty + i * 4][tx] = W1[(size_t)(r0 + ty + i * 4) * FF + (c0 + tx)];
    __syncthreads();
#pragma unroll
    for (int i = 0; i < 16; ++i)
      W1t[(size_t)(c0 + ty + i * 4) * HID + (r0 + tx)] =
          __float2bfloat16(tile[tx][ty + i * 4]);
    return;
  }

  // -------- gate + compact + zero dropped rows --------
  const int gb = bid - NBT1;
  const int t0 = gb * GTOK;
  const int wave = tid >> 6, lane = tid & 63;

  float4 gv[4];
#pragma unroll
  for (int it = 0; it < 4; ++it) gv[it] = ((const float4*)wg)[it * 64 + lane];

  // hold h rows in registers across both passes (64 VGPR)
  float4 hv[4][4];
  __shared__ float slogit[GTOK];
  __shared__ int sslot[GTOK];

#pragma unroll
  for (int r = 0; r < 4; ++r) {
    const int li = r * 4 + wave;
    const float* hrow = h + (size_t)(t0 + li) * HID;
    float d = 0.f;
#pragma unroll
    for (int it = 0; it < 4; ++it) {
      hv[r][it] = ((const float4*)hrow)[it * 64 + lane];
      d += hv[r][it].x * gv[it].x + hv[r][it].y * gv[it].y +
           hv[r][it].z * gv[it].z + hv[r][it].w * gv[it].w;
    }
#pragma unroll
    for (int o = 32; o > 0; o >>= 1) d += __shfl_down(d, o, 64);
    if (lane == 0) slogit[li] = d;
  }
  __syncthreads();

  if (tid == 0) {  // prefix over 16 keep flags; ONE atomic per block
    const float bg = bgp[0];
    int slots[GTOK];
    int n = 0;
#pragma unroll
    for (int li = 0; li < GTOK; ++li) {
      const bool keep = (slogit[li] + bg >= 0.0f) || (labels[t0 + li] == -100);
      slots[li] = keep ? n++ : -1;
    }
    const int base = atomicAdd(cnt, n);
#pragma unroll
    for (int li = 0; li < GTOK; ++li)
      sslot[li] = slots[li] >= 0 ? base + slots[li] : -1;
  }
  __syncthreads();

#pragma unroll
  for (int r = 0; r < 4; ++r) {
    const int li = r * 4 + wave;
    const int t = t0 + li;
    const int m = sslot[li];
    if (m >= 0) {
      if (lane == 0) idx[m] = t;
      const float logit = slogit[li] + bgp[0];
      const float w = 1.0f / (1.0f + __expf(-logit));
#pragma unroll
      for (int it = 0; it < 4; ++it) {
        union { ushort4 u; __hip_bfloat16 b[4]; } pk;
        pk.b[0] = __float2bfloat16(hv[r][it].x * w);
        pk.b[1] = __float2bfloat16(hv[r][it].y * w);
        pk.b[2] = __float2bfloat16(hv[r][it].z * w);
        pk.b[3] = __float2bfloat16(hv[r][it].w * w);
        ((ushort4*)(A + (size_t)m * HID))[it * 64 + lane] = pk.u;
      }
    } else {
      const float4 z = make_float4(0.f, 0.f, 0.f, 0.f);
#pragma unroll
      for (int it = 0; it < 4; ++it)
        ((float4*)(out + (size_t)t * HID))[it * 64 + lane] = z;
    }
  }
}

// ---------------- GEMM LDS swizzle (both GEMMs) ----------------
// LDS rows of 64 k-elems (128 B). Staging: lane l covers row
// r = wbase + c*8 + (l>>3), source chunk g = (l&7) ^ (r&7), stored at
// position l&7. Read of chunk ck of row r at position ck ^ (r&7); fragment
// reads touch 16 rows x 4 chunks per instruction -> 2-way bank aliasing
// only (free; measured 0 conflicts). NOTE: 32x32 MFMA layout (32 rows x
// 2 chunks) is 4-way conflicted in this scheme — do not use (R12).

// GEMM1 dispatch: blocks [0,1024) transpose W2[FF][HID]->W2t[HID][FF]
// (overlaps with gemm compute; W2t only needed by gemm2); blocks
// [1024,5120) = 128x128-tile GEMM, single-buffered (R6-proven, ~9
// active blocks/CU -> cross-block latency hiding).
#define NBT2 1024  // (HID/64)*(FF/64)

__global__ __launch_bounds__(256, 2) void k_gemm1(const __hip_bfloat16* __restrict__ A,
                                                  const __hip_bfloat16* __restrict__ Bt,
                                                  const float* __restrict__ bias,
                                                  __hip_bfloat16* __restrict__ Act,
                                                  const int* __restrict__ cnt,
                                                  const float* __restrict__ W2,
                                                  __hip_bfloat16* __restrict__ W2t) {
  __shared__ char smem[32768];           // union: gemm lA|lB, transpose tile
  const int bid = blockIdx.x;
  const int tid = threadIdx.x;

  if (bid < NBT2) {
    // -------- transpose W2[FF][HID] fp32 -> W2t[HID][FF] bf16 --------
    float (*tile)[65] = (float(*)[65])smem;   // 64x65 fp32 = 16.25 KiB
    const int nbc = HID / 64;
    const int c0 = (bid % nbc) * 64, r0 = (bid / nbc) * 64;
    const int tx = tid & 63, ty = tid >> 6;
#pragma unroll
    for (int i = 0; i < 16; ++i)
      tile[ty + i * 4][tx] = W2[(size_t)(r0 + ty + i * 4) * HID + (c0 + tx)];
    __syncthreads();
#pragma unroll
    for (int i = 0; i < 16; ++i)
      W2t[(size_t)(c0 + ty + i * 4) * FF + (r0 + tx)] =
          __float2bfloat16(tile[tx][ty + i * 4]);
    return;
  }

  const int g = bid - NBT2;
  const int Mc = *cnt;
  const int m0 = (g & 127) * 128;        // m-fast: consecutive blocks share B panel
  if (m0 >= Mc) return;
  const int n0 = (g >> 7) * 128;

  __hip_bfloat16* lA = (__hip_bfloat16*)smem;            // 16 KiB
  __hip_bfloat16* lB = (__hip_bfloat16*)(smem + 16384);  // 16 KiB

  const int wave = tid >> 6, lane = tid & 63;
  const int wr = (wave >> 1) * 64, wc = (wave & 1) * 64;
  const int fm = lane & 15, quad = lane >> 4;

  const int srow = (lane >> 3);                       // 0..7
  const int sg   = ((lane & 7) ^ srow) * 8;           // global elem offset

  f32x4 acc[4][4] = {};

  const __hip_bfloat16* gA = A  + (size_t)(m0 + wave * 32 + srow) * HID + sg;
  const __hip_bfloat16* gB = Bt + (size_t)(n0 + wave * 32 + srow) * HID + sg;
  char* dA = (char*)lA + wave * 4096;
  char* dB = (char*)lB + wave * 4096;

  for (int kt = 0; kt < HID; kt += 64) {
    __syncthreads();
#pragma unroll
    for (int c = 0; c < 4; ++c) {
      gload_lds16(gA + (size_t)(c * 8) * HID + kt, dA + c * 1024);
      gload_lds16(gB + (size_t)(c * 8) * HID + kt, dB + c * 1024);
    }
    __syncthreads();
#pragma unroll
    for (int ks = 0; ks < 2; ++ks) {
      bf16x8 af[4], bb[4];
#pragma unroll
      for (int i = 0; i < 4; ++i)
        af[i] = *(const bf16x8*)&lA[(wr + i * 16 + fm) * 64 + (((ks * 4 + quad) ^ (fm & 7)) * 8)];
#pragma unroll
      for (int j = 0; j < 4; ++j)
        bb[j] = *(const bf16x8*)&lB[(wc + j * 16 + fm) * 64 + (((ks * 4 + quad) ^ (fm & 7)) * 8)];
#pragma unroll
      for (int i = 0; i < 4; ++i)
#pragma unroll
        for (int j = 0; j < 4; ++j)
          acc[i][j] = __builtin_amdgcn_mfma_f32_16x16x32_bf16(af[i], bb[j], acc[i][j], 0, 0, 0);
    }
  }

#pragma unroll
  for (int j = 0; j < 4; ++j) {
    const int col = n0 + wc + j * 16 + fm;
    const float bv = bias[col];
#pragma unroll
    for (int i = 0; i < 4; ++i) {
      const int rbase = m0 + wr + i * 16 + quad * 4;
#pragma unroll
      for (int r = 0; r < 4; ++r) {
        float v = acc[i][j][r] + bv;
        v = v > 0.f ? v : 0.f;
        Act[(size_t)(rbase + r) * FF + col] = __float2bfloat16(v);
      }
    }
  }
}

// GEMM2: out[idx[m]] = Act @ W2t^T + b2, fp32 scatter. K=FF=4096.
// EXACT R6 version (106.8us plateau): BM=64 x BN=128, single-buffered,
// ~1144 active blocks (4.5/CU), 24 KiB LDS, 16x16 MFMA.
__global__ __launch_bounds__(256, 4) void k_gemm2(const __hip_bfloat16* __restrict__ Act,
                                                  const __hip_bfloat16* __restrict__ Bt,
                                                  const float* __restrict__ bias,
                                                  const int* __restrict__ idx,
                                                  float* __restrict__ out,
                                                  const int* __restrict__ cnt) {
  const int Mc = *cnt;
  const int m0 = blockIdx.x * 64;
  if (m0 >= Mc) return;
  const int n0 = blockIdx.y * 128;

  __shared__ __hip_bfloat16 lA[64 * 64];   // 8 KiB
  __shared__ __hip_bfloat16 lB[128 * 64];  // 16 KiB

  const int tid = threadIdx.x;
  const int wave = tid >> 6, lane = tid & 63;
  const int wr = (wave >> 1) * 32, wc = (wave & 1) * 64;
  const int fm = lane & 15, quad = lane >> 4;
  const int srow = (lane >> 3);
  const int sg   = ((lane & 7) ^ srow) * 8;

  f32x4 acc[2][4] = {};

  const __hip_bfloat16* gA = Act + (size_t)(m0 + wave * 16 + srow) * FF + sg;
  const __hip_bfloat16* gB = Bt  + (size_t)(n0 + wave * 32 + srow) * FF + sg;
  char* dA = (char*)lA + wave * 2048;
  char* dB = (char*)lB + wave * 4096;

  for (int kt = 0; kt < FF; kt += 64) {
    __syncthreads();
#pragma unroll
    for (int c = 0; c < 2; ++c)
      gload_lds16(gA + (size_t)(c * 8) * FF + kt, dA + c * 1024);
#pragma unroll
    for (int c = 0; c < 4; ++c)
      gload_lds16(gB + (size_t)(c * 8) * FF + kt, dB + c * 1024);
    __syncthreads();
#pragma unroll
    for (int ks = 0; ks < 2; ++ks) {
      bf16x8 af[2], bb[4];
#pragma unroll
      for (int i = 0; i < 2; ++i)
        af[i] = *(const bf16x8*)&lA[(wr + i * 16 + fm) * 64 + (((ks * 4 + quad) ^ (fm & 7)) * 8)];
#pragma unroll
      for (int j = 0; j < 4; ++j)
        bb[j] = *(const bf16x8*)&lB[(wc + j * 16 + fm) * 64 + (((ks * 4 + quad) ^ (fm & 7)) * 8)];
#pragma unroll
      for (int i = 0; i < 2; ++i)
#pragma unroll
        for (int j = 0; j < 4; ++j)
          acc[i][j] = __builtin_amdgcn_mfma_f32_16x16x32_bf16(af[i], bb[j], acc[i][j], 0, 0, 0);
    }
  }

#pragma unroll
  for (int i = 0; i < 2; ++i) {
#pragma unroll
    for (int r = 0; r < 4; ++r) {
      const int m = m0 + wr + i * 16 + quad * 4 + r;
      if (m < Mc) {
        const int t = idx[m];
        float* orow = out + (size_t)t * HID + n0 + wc + fm;
#pragma unroll
        for (int j = 0; j < 4; ++j)
          orow[j * 16] = acc[i][j][r] + bias[n0 + wc + j * 16 + fm];
      }
    }
  }
}

// ---------------- launch ----------------
extern "C" void kernel_launch(void* const* d_in, const int* in_sizes, int n_in,
                              void* d_out, int out_size, void* d_ws, size_t ws_size,
                              hipStream_t stream) {
  const float* h   = (const float*)d_in[0];
  const float* Wg  = (const float*)d_in[3];
  const float* bg  = (const float*)d_in[4];
  const float* W1  = (const float*)d_in[5];
  const float* b1  = (const float*)d_in[6];
  const float* W2  = (const float*)d_in[7];
  const float* b2  = (const float*)d_in[8];
  const int*  labels = (const int*)d_in[9];
  float* out = (float*)d_out;

  char* ws = (char*)d_ws;
  int* cnt            = (int*)(ws + 0);
  int* idx            = (int*)(ws + 1024);
  __hip_bfloat16* W1t = (__hip_bfloat16*)(ws + (1u  << 17));   // [FF][HID]
  __hip_bfloat16* W2t = (__hip_bfloat16*)(ws + (16u << 20));   // [HID][FF]
  __hip_bfloat16* A   = (__hip_bfloat16*)(ws + (32u << 20));   // [TOK][HID]
  __hip_bfloat16* Act = (__hip_bfloat16*)(ws + (64ull << 20)); // [TOK][FF]

  hipMemsetAsync(cnt, 0, 4, stream);
  k_pre<<<NBT1 + TOK / GTOK, 256, 0, stream>>>(W1, W1t, h, Wg, bg, labels,
                                               out, A, idx, cnt);
  k_gemm1<<<NBT2 + (TOK / 128) * (FF / 128), 256, 0, stream>>>(A, W1t, b1, Act,
                                                               cnt, W2, W2t);
  k_gemm2<<<dim3(TOK / 64, HID / 128), 256, 0, stream>>>(Act, W2t, b2, idx, out, cnt);
}